// Round 1
// baseline (3847.445 us; speedup 1.0000x reference)
//
#include <hip/hip_runtime.h>
#include <math.h>

// ---------------------------------------------------------------------------
// LongNetViT forward, fp32 correctness-first baseline.
// L=4096 (cls + 4095 tokens), D=256, H=8, HD=32, DEPTH=4.
// Dilated attention branches at L=4096:
//   b0: r=1,  we=1024, segs=4, m=1024
//   b1: r=2,  we=4096, segs=1, m=2048
//   b2: r=4,  we=4096, segs=1, m=1024
//   b3: r=8,  we=4096, segs=1, m=512
//   b4: r=16, we=4096, segs=1, m=256
// No padding anywhere (4096 % we == 0), all masks valid.
// ---------------------------------------------------------------------------

__device__ __forceinline__ float wred_max(float v) {
#pragma unroll
  for (int o = 32; o; o >>= 1) v = fmaxf(v, __shfl_xor(v, o));
  return v;
}
__device__ __forceinline__ float wred_sum(float v) {
#pragma unroll
  for (int o = 32; o; o >>= 1) v += __shfl_xor(v, o);
  return v;
}

// ---------------------------------------------------------------------------
// Generic fp32 GEMM: C[M,N] = epi(A[M,K] @ B[K,N] + bias[N])
// EPI: 0 = none, 1 = exact GELU, 2 = residual add (C += ...)
// BM=BN=64, BK=16, 256 threads, 4x4 micro-tile per thread.
// ---------------------------------------------------------------------------
template <int EPI>
__global__ __launch_bounds__(256) void gemm_kernel(
    const float* __restrict__ A, const float* __restrict__ Bw,
    const float* __restrict__ bias, float* __restrict__ C,
    int M, int N, int K) {
  __shared__ float As[16][64];  // transposed A tile: As[k][row]
  __shared__ float Bs[16][64];  // Bs[k][col]

  const int t = threadIdx.x;
  const int tx = t & 15, ty = t >> 4;
  const int bm = blockIdx.x * 64, bn = blockIdx.y * 64;

  const int arow = t >> 2, ac4 = t & 3;   // A stage: 64 rows x 4 float4
  const int brow = t >> 4, bc4 = t & 15;  // B stage: 16 rows x 16 float4

  float acc[4][4];
#pragma unroll
  for (int i = 0; i < 4; i++)
#pragma unroll
    for (int j = 0; j < 4; j++) acc[i][j] = 0.f;

  for (int k0 = 0; k0 < K; k0 += 16) {
    float4 a4 = make_float4(0.f, 0.f, 0.f, 0.f);
    if (bm + arow < M)
      a4 = *(const float4*)(A + (size_t)(bm + arow) * K + k0 + ac4 * 4);
    float4 b4 = *(const float4*)(Bw + (size_t)(k0 + brow) * N + bn + bc4 * 4);

    __syncthreads();  // previous-iteration LDS reads must be done
    As[ac4 * 4 + 0][arow] = a4.x;
    As[ac4 * 4 + 1][arow] = a4.y;
    As[ac4 * 4 + 2][arow] = a4.z;
    As[ac4 * 4 + 3][arow] = a4.w;
    *(float4*)&Bs[brow][bc4 * 4] = b4;
    __syncthreads();

#pragma unroll
    for (int k = 0; k < 16; k++) {
      float4 avv = *(const float4*)&As[k][ty * 4];
      float4 bvv = *(const float4*)&Bs[k][tx * 4];
      float av[4] = {avv.x, avv.y, avv.z, avv.w};
      float bv[4] = {bvv.x, bvv.y, bvv.z, bvv.w};
#pragma unroll
      for (int i = 0; i < 4; i++)
#pragma unroll
        for (int j = 0; j < 4; j++) acc[i][j] += av[i] * bv[j];
    }
  }

  float4 bias4 = *(const float4*)(bias + bn + tx * 4);
  float bb[4] = {bias4.x, bias4.y, bias4.z, bias4.w};
#pragma unroll
  for (int i = 0; i < 4; i++) {
    int row = bm + ty * 4 + i;
    if (row < M) {
      float c[4];
#pragma unroll
      for (int j = 0; j < 4; j++) c[j] = acc[i][j] + bb[j];
      if (EPI == 1) {
#pragma unroll
        for (int j = 0; j < 4; j++)
          c[j] = 0.5f * c[j] * (1.f + erff(c[j] * 0.70710678118654752f));
      }
      float* cp = C + (size_t)row * N + bn + tx * 4;
      if (EPI == 2) {
        float4 old = *(const float4*)cp;
        c[0] += old.x; c[1] += old.y; c[2] += old.z; c[3] += old.w;
      }
      *(float4*)cp = make_float4(c[0], c[1], c[2], c[3]);
    }
  }
}

// ---------------------------------------------------------------------------
// LayerNorm over D=256; one wave per row, 4 rows per block.
// ---------------------------------------------------------------------------
__global__ __launch_bounds__(256) void ln_kernel(
    const float* __restrict__ x, const float* __restrict__ w,
    const float* __restrict__ b, float* __restrict__ y) {
  const int row = blockIdx.x * 4 + (threadIdx.x >> 6);
  const int lane = threadIdx.x & 63;
  float4 v = *(const float4*)(x + (size_t)row * 256 + lane * 4);
  float s1 = v.x + v.y + v.z + v.w;
  float s2 = v.x * v.x + v.y * v.y + v.z * v.z + v.w * v.w;
  s1 = wred_sum(s1);
  s2 = wred_sum(s2);
  float mu = s1 * (1.f / 256.f);
  float var = s2 * (1.f / 256.f) - mu * mu;
  float inv = rsqrtf(var + 1e-5f);
  float4 wv = *(const float4*)(w + lane * 4);
  float4 bv = *(const float4*)(b + lane * 4);
  float4 o;
  o.x = (v.x - mu) * inv * wv.x + bv.x;
  o.y = (v.y - mu) * inv * wv.y + bv.y;
  o.z = (v.z - mu) * inv * wv.z + bv.z;
  o.w = (v.w - mu) * inv * wv.w + bv.w;
  *(float4*)(y + (size_t)row * 256 + lane * 4) = o;
}

// ---------------------------------------------------------------------------
// Assemble h: h[0] = cls + pe[0]; h[1+i] += pe[pos(coords_i)]  (GEMM already
// wrote patch embed + bias into h[1..4095]).
// ---------------------------------------------------------------------------
__global__ __launch_bounds__(64) void assemble_kernel(
    const float* __restrict__ coords, const float* __restrict__ cls,
    const float* __restrict__ pe, float* __restrict__ h) {
  const int i = blockIdx.x;
  const int lane = threadIdx.x;
  if (i == 0) {
    float4 c = *(const float4*)(cls + lane * 4);
    float4 p = *(const float4*)(pe + lane * 4);
    *(float4*)(h + lane * 4) =
        make_float4(c.x + p.x, c.y + p.y, c.z + p.z, c.w + p.w);
  } else {
    int g0 = (int)floorf(coords[(size_t)(i - 1) * 2 + 0] * (1.f / 256.f));
    int g1 = (int)floorf(coords[(size_t)(i - 1) * 2 + 1] * (1.f / 256.f));
    int pos = g0 * 512 + g1 + 1;
    float4 p = *(const float4*)(pe + (size_t)pos * 256 + lane * 4);
    float4 hv = *(const float4*)(h + (size_t)i * 256 + lane * 4);
    *(float4*)(h + (size_t)i * 256 + lane * 4) =
        make_float4(hv.x + p.x, hv.y + p.y, hv.z + p.z, hv.w + p.w);
  }
}

// ---------------------------------------------------------------------------
// Dilated attention, all 5 branches in one launch. 1984 blocks:
// [0,1024) b0 | [1024,1536) b1 | [1536,1792) b2 | [1792,1920) b3 | [1920,1984) b4
// Block: 256 thr = 4 waves; 32 q-rows/block (8 per wave); K/V tiles of 64 keys
// staged in XOR-swizzled LDS (b128 bank-floor); online softmax per q-row with
// score-per-lane layout; PV via p broadcast from LDS, lane = (dim4, key-half).
// Writes normalized per-branch output + lse.
// ---------------------------------------------------------------------------
__global__ __launch_bounds__(256) void attn_kernel(
    const float* __restrict__ qkv, float* __restrict__ out_all,
    float* __restrict__ lse_all) {
  __shared__ float4 Qs[32][8];
  __shared__ float4 Ks[64][8];
  __shared__ float4 Vs[64][8];
  __shared__ float Ps[4][64];

  const int bid = blockIdx.x;
  int b, r, m, off, base, h, qt;
  if (bid < 1024) {
    b = 0; int loc = bid; int s = loc >> 8; int rem = loc & 255;
    h = rem >> 5; qt = rem & 31; r = 1; m = 1024; base = s * 1024; off = 0;
  } else if (bid < 1536) {
    b = 1; int loc = bid - 1024; h = loc >> 6; qt = loc & 63;
    r = 2; m = 2048; base = 0; off = h & 1;
  } else if (bid < 1792) {
    b = 2; int loc = bid - 1536; h = loc >> 5; qt = loc & 31;
    r = 4; m = 1024; base = 0; off = h & 3;
  } else if (bid < 1920) {
    b = 3; int loc = bid - 1792; h = loc >> 4; qt = loc & 15;
    r = 8; m = 512; base = 0; off = h & 7;
  } else {
    b = 4; int loc = bid - 1920; h = loc >> 3; qt = loc & 7;
    r = 16; m = 256; base = 0; off = h;  // h < 8, h % 16 == h
  }

  const int t = threadIdx.x;
  const int wid = t >> 6, lane = t & 63;
  const int q0 = qt * 32;

  {  // stage Q tile (32 rows x 32 floats)
    int row = t >> 3, c4 = t & 7;
    int p = base + off + r * (q0 + row);
    Qs[row][c4] = *(const float4*)(qkv + (size_t)p * 768 + h * 32 + c4 * 4);
  }

  float4 acc[8];
  float rm[8], rl[8];
#pragma unroll
  for (int i = 0; i < 8; i++) {
    acc[i] = make_float4(0.f, 0.f, 0.f, 0.f);
    rm[i] = -1e30f;
    rl[i] = 0.f;
  }

  const float scale = 0.17677669529663687f;  // 1/sqrt(32)
  const int ntiles = m >> 6;
  const int d4i = lane & 7;   // which float4 of the 32-dim output
  const int kh = lane >> 3;   // key-half group (8 groups of 8 keys)
  const int rbase = wid * 8;

  for (int kt = 0; kt < ntiles; ++kt) {
    __syncthreads();  // previous tile fully consumed (also covers Q staging)
#pragma unroll
    for (int rep = 0; rep < 2; ++rep) {
      int g = rep * 256 + t;
      int row = g >> 3, c4 = g & 7;
      int p = base + off + r * (kt * 64 + row);
      const float* kb = qkv + (size_t)p * 768 + 256 + h * 32;
      Ks[row][c4 ^ (row & 7)] = *(const float4*)(kb + c4 * 4);
      Vs[row][c4 ^ ((row >> 3) & 7)] = *(const float4*)(kb + 256 + c4 * 4);
    }
    __syncthreads();

#pragma unroll
    for (int q = 0; q < 8; q++) {
      float s = 0.f;
#pragma unroll
      for (int j = 0; j < 8; j++) {
        float4 qv = Qs[rbase + q][j];                // broadcast
        float4 kv = Ks[lane][j ^ (lane & 7)];        // swizzled, bank-floor
        s += qv.x * kv.x + qv.y * kv.y + qv.z * kv.z + qv.w * kv.w;
      }
      s *= scale;
      float mx = wred_max(s);
      float nm = fmaxf(rm[q], mx);
      float pv = __expf(s - nm);
      float corr = __expf(rm[q] - nm);
      rm[q] = nm;
      rl[q] = rl[q] * corr + wred_sum(pv);
      acc[q].x *= corr; acc[q].y *= corr; acc[q].z *= corr; acc[q].w *= corr;
      Ps[wid][lane] = pv;  // DS ops in-order within a wave
#pragma unroll
      for (int k = 0; k < 8; k++) {
        int key = kh * 8 + k;
        float pk = Ps[wid][key];                     // 8-lane broadcast
        float4 vv = Vs[key][d4i ^ (key >> 3)];       // swizzled
        acc[q].x += pk * vv.x; acc[q].y += pk * vv.y;
        acc[q].z += pk * vv.z; acc[q].w += pk * vv.w;
      }
    }
  }

#pragma unroll
  for (int q = 0; q < 8; q++) {
    float4 a = acc[q];
#pragma unroll
    for (int o = 8; o < 64; o <<= 1) {  // reduce across key-half groups
      a.x += __shfl_xor(a.x, o); a.y += __shfl_xor(a.y, o);
      a.z += __shfl_xor(a.z, o); a.w += __shfl_xor(a.w, o);
    }
    if (kh == 0) {
      float inv = 1.f / rl[q];
      int pos = base + off + r * (q0 + rbase + q);
      size_t ob = (((size_t)b * 4096 + pos) * 8 + h) * 32 + d4i * 4;
      *(float4*)(out_all + ob) =
          make_float4(a.x * inv, a.y * inv, a.z * inv, a.w * inv);
      if (d4i == 0)
        lse_all[((size_t)b * 4096 + pos) * 8 + h] = rm[q] + __logf(rl[q]);
    }
  }
}

// ---------------------------------------------------------------------------
// Combine the 5 branch outputs per (pos, head) by LSE softmax weighting.
// Branch b covers (pos,h) iff (pos ^ h) & (r_b - 1) == 0.
// ---------------------------------------------------------------------------
__global__ __launch_bounds__(256) void combine_kernel(
    const float* __restrict__ out_all, const float* __restrict__ lse_all,
    float* __restrict__ att) {
  const int tid = blockIdx.x * 256 + threadIdx.x;
  const int pos = tid >> 8;
  const int ph = (tid >> 5) & 7;
  const int d = tid & 31;

  float lse[5];
  bool cov[5];
#pragma unroll
  for (int b = 0; b < 5; b++) {
    int rr = 1 << b;
    cov[b] = ((pos ^ ph) & (rr - 1)) == 0;
    lse[b] = cov[b] ? lse_all[((size_t)b * 4096 + pos) * 8 + ph] : -3.0e38f;
  }
  float mx = lse[0];
#pragma unroll
  for (int b = 1; b < 5; b++) mx = fmaxf(mx, lse[b]);
  float wsum = 0.f, o = 0.f;
#pragma unroll
  for (int b = 0; b < 5; b++) {
    if (cov[b]) {
      float w = __expf(lse[b] - mx);
      wsum += w;
      o += w * out_all[(((size_t)b * 4096 + pos) * 8 + ph) * 32 + d];
    }
  }
  att[(size_t)pos * 256 + ph * 32 + d] = o / wsum;
}

// ---------------------------------------------------------------------------
// Final: out = LN(LN(h[0], encln), norm). One wave.
// ---------------------------------------------------------------------------
__global__ __launch_bounds__(64) void final_kernel(
    const float* __restrict__ h, const float* __restrict__ ew,
    const float* __restrict__ eb, const float* __restrict__ nw,
    const float* __restrict__ nb, float* __restrict__ out) {
  const int lane = threadIdx.x;
  float4 v = *(const float4*)(h + lane * 4);
  float s1 = wred_sum(v.x + v.y + v.z + v.w);
  float s2 = wred_sum(v.x * v.x + v.y * v.y + v.z * v.z + v.w * v.w);
  float mu = s1 * (1.f / 256.f);
  float inv = rsqrtf(s2 * (1.f / 256.f) - mu * mu + 1e-5f);
  float4 wv = *(const float4*)(ew + lane * 4);
  float4 bv = *(const float4*)(eb + lane * 4);
  float4 tv;
  tv.x = (v.x - mu) * inv * wv.x + bv.x;
  tv.y = (v.y - mu) * inv * wv.y + bv.y;
  tv.z = (v.z - mu) * inv * wv.z + bv.z;
  tv.w = (v.w - mu) * inv * wv.w + bv.w;
  s1 = wred_sum(tv.x + tv.y + tv.z + tv.w);
  s2 = wred_sum(tv.x * tv.x + tv.y * tv.y + tv.z * tv.z + tv.w * tv.w);
  mu = s1 * (1.f / 256.f);
  inv = rsqrtf(s2 * (1.f / 256.f) - mu * mu + 1e-5f);
  float4 w2v = *(const float4*)(nw + lane * 4);
  float4 b2v = *(const float4*)(nb + lane * 4);
  float4 o;
  o.x = (tv.x - mu) * inv * w2v.x + b2v.x;
  o.y = (tv.y - mu) * inv * w2v.y + b2v.y;
  o.z = (tv.z - mu) * inv * w2v.z + b2v.z;
  o.w = (tv.w - mu) * inv * w2v.w + b2v.w;
  *(float4*)(out + lane * 4) = o;
}

// ---------------------------------------------------------------------------

extern "C" void kernel_launch(void* const* d_in, const int* in_sizes, int n_in,
                              void* d_out, int out_size, void* d_ws,
                              size_t ws_size, hipStream_t stream) {
  const float* x      = (const float*)d_in[0];
  const float* coords = (const float*)d_in[1];
  const float* pw     = (const float*)d_in[2];
  const float* pb     = (const float*)d_in[3];
  const float* cls    = (const float*)d_in[4];
  const float* pe     = (const float*)d_in[5];
  const float* ln1w   = (const float*)d_in[6];
  const float* ln1b   = (const float*)d_in[7];
  const float* wqkv   = (const float*)d_in[8];
  const float* bqkv   = (const float*)d_in[9];
  const float* wo     = (const float*)d_in[10];
  const float* bo     = (const float*)d_in[11];
  const float* ln2w   = (const float*)d_in[12];
  const float* ln2b   = (const float*)d_in[13];
  const float* w1     = (const float*)d_in[14];
  const float* b1     = (const float*)d_in[15];
  const float* w2     = (const float*)d_in[16];
  const float* b2     = (const float*)d_in[17];
  const float* encw   = (const float*)d_in[18];
  const float* encb   = (const float*)d_in[19];
  const float* nw     = (const float*)d_in[20];
  const float* nb     = (const float*)d_in[21];

  float* ws      = (float*)d_ws;
  float* h       = ws;                   // 4096*256      = 1,048,576
  float* hn      = h + 1048576;          // 1,048,576
  float* qkv     = hn + 1048576;         // 4096*768      = 3,145,728
  float* out_all = qkv + 3145728;        // 5*4096*256    = 5,242,880
  float* lse     = out_all + 5242880;    // 5*4096*8      = 163,840 (pad 262144)
  float* att     = lse + 262144;         // 1,048,576
  float* mid     = att + 1048576;        // 4096*1024     = 4,194,304
  // total: 15,990,784 floats ~= 61 MiB

  // patch embed -> h[1..4095]
  gemm_kernel<0><<<dim3(64, 4), 256, 0, stream>>>(x, pw, pb, h + 256, 4095, 256, 1536);
  // cls + pos-embed gather
  assemble_kernel<<<4096, 64, 0, stream>>>(coords, cls, pe, h);

  for (int l = 0; l < 4; l++) {
    ln_kernel<<<1024, 256, 0, stream>>>(h, ln1w + l * 256, ln1b + l * 256, hn);
    gemm_kernel<0><<<dim3(64, 12), 256, 0, stream>>>(
        hn, wqkv + (size_t)l * 196608, bqkv + l * 768, qkv, 4096, 768, 256);
    attn_kernel<<<1984, 256, 0, stream>>>(qkv, out_all, lse);
    combine_kernel<<<4096, 256, 0, stream>>>(out_all, lse, att);
    gemm_kernel<2><<<dim3(64, 4), 256, 0, stream>>>(
        att, wo + (size_t)l * 65536, bo + l * 256, h, 4096, 256, 256);
    ln_kernel<<<1024, 256, 0, stream>>>(h, ln2w + l * 256, ln2b + l * 256, hn);
    gemm_kernel<1><<<dim3(64, 16), 256, 0, stream>>>(
        hn, w1 + (size_t)l * 262144, b1 + l * 1024, mid, 4096, 1024, 256);
    gemm_kernel<2><<<dim3(64, 4), 256, 0, stream>>>(
        mid, w2 + (size_t)l * 262144, b2 + l * 256, h, 4096, 256, 1024);
  }

  final_kernel<<<1, 64, 0, stream>>>(h, encw, encb, nw, nb, (float*)d_out);
}

// Round 2
// 1082.611 us; speedup vs baseline: 3.5539x; 3.5539x over previous
//
#include <hip/hip_runtime.h>
#include <hip/hip_bf16.h>
#include <math.h>

// ---------------------------------------------------------------------------
// LongNetViT forward. L=4096 (cls+4095), D=256, H=8, HD=32, DEPTH=4.
// Attention: bf16 MFMA flash attention, zero LDS in the inner loop.
// Branches at L=4096 (no padding):
//   b0: r=1  m=1024 segs=4 | b1: r=2 m=2048 | b2: r=4 m=1024
//   b3: r=8  m=512         | b4: r=16 m=256
// ---------------------------------------------------------------------------

typedef __attribute__((ext_vector_type(8))) short short8;
typedef __attribute__((ext_vector_type(4))) float f32x4;

__device__ __forceinline__ float wred_sum(float v) {
#pragma unroll
  for (int o = 32; o; o >>= 1) v += __shfl_xor(v, o);
  return v;
}

__device__ __forceinline__ unsigned short f2bf(float x) {
  unsigned u = __float_as_uint(x);
  u += 0x7FFF + ((u >> 16) & 1);
  return (unsigned short)(u >> 16);
}

// ---------------------------------------------------------------------------
// Generic fp32 GEMM: C[M,N] = epi(A[M,K] @ B[K,N] + bias[N])
// EPI: 0 = none, 1 = exact GELU, 2 = residual add, 3 = bf16 output
// ---------------------------------------------------------------------------
template <int EPI>
__global__ __launch_bounds__(256) void gemm_kernel(
    const float* __restrict__ A, const float* __restrict__ Bw,
    const float* __restrict__ bias, void* __restrict__ Cv,
    int M, int N, int K) {
  __shared__ float As[16][64];
  __shared__ float Bs[16][64];

  const int t = threadIdx.x;
  const int tx = t & 15, ty = t >> 4;
  const int bm = blockIdx.x * 64, bn = blockIdx.y * 64;

  const int arow = t >> 2, ac4 = t & 3;
  const int brow = t >> 4, bc4 = t & 15;

  float acc[4][4];
#pragma unroll
  for (int i = 0; i < 4; i++)
#pragma unroll
    for (int j = 0; j < 4; j++) acc[i][j] = 0.f;

  for (int k0 = 0; k0 < K; k0 += 16) {
    float4 a4 = make_float4(0.f, 0.f, 0.f, 0.f);
    if (bm + arow < M)
      a4 = *(const float4*)(A + (size_t)(bm + arow) * K + k0 + ac4 * 4);
    float4 b4 = *(const float4*)(Bw + (size_t)(k0 + brow) * N + bn + bc4 * 4);

    __syncthreads();
    As[ac4 * 4 + 0][arow] = a4.x;
    As[ac4 * 4 + 1][arow] = a4.y;
    As[ac4 * 4 + 2][arow] = a4.z;
    As[ac4 * 4 + 3][arow] = a4.w;
    *(float4*)&Bs[brow][bc4 * 4] = b4;
    __syncthreads();

#pragma unroll
    for (int k = 0; k < 16; k++) {
      float4 avv = *(const float4*)&As[k][ty * 4];
      float4 bvv = *(const float4*)&Bs[k][tx * 4];
      float av[4] = {avv.x, avv.y, avv.z, avv.w};
      float bv[4] = {bvv.x, bvv.y, bvv.z, bvv.w};
#pragma unroll
      for (int i = 0; i < 4; i++)
#pragma unroll
        for (int j = 0; j < 4; j++) acc[i][j] += av[i] * bv[j];
    }
  }

  float4 bias4 = *(const float4*)(bias + bn + tx * 4);
  float bb[4] = {bias4.x, bias4.y, bias4.z, bias4.w};
#pragma unroll
  for (int i = 0; i < 4; i++) {
    int row = bm + ty * 4 + i;
    if (row < M) {
      float c[4];
#pragma unroll
      for (int j = 0; j < 4; j++) c[j] = acc[i][j] + bb[j];
      if (EPI == 1) {
#pragma unroll
        for (int j = 0; j < 4; j++)
          c[j] = 0.5f * c[j] * (1.f + erff(c[j] * 0.70710678118654752f));
      }
      if (EPI == 3) {
        unsigned short* cp =
            (unsigned short*)Cv + (size_t)row * N + bn + tx * 4;
        unsigned u0 = (unsigned)f2bf(c[0]) | ((unsigned)f2bf(c[1]) << 16);
        unsigned u1 = (unsigned)f2bf(c[2]) | ((unsigned)f2bf(c[3]) << 16);
        *(uint2*)cp = make_uint2(u0, u1);
      } else {
        float* cp = (float*)Cv + (size_t)row * N + bn + tx * 4;
        if (EPI == 2) {
          float4 old = *(const float4*)cp;
          c[0] += old.x; c[1] += old.y; c[2] += old.z; c[3] += old.w;
        }
        *(float4*)cp = make_float4(c[0], c[1], c[2], c[3]);
      }
    }
  }
}

// ---------------------------------------------------------------------------
// LayerNorm over D=256; one wave per row, 4 rows per block.
// ---------------------------------------------------------------------------
__global__ __launch_bounds__(256) void ln_kernel(
    const float* __restrict__ x, const float* __restrict__ w,
    const float* __restrict__ b, float* __restrict__ y) {
  const int row = blockIdx.x * 4 + (threadIdx.x >> 6);
  const int lane = threadIdx.x & 63;
  float4 v = *(const float4*)(x + (size_t)row * 256 + lane * 4);
  float s1 = wred_sum(v.x + v.y + v.z + v.w);
  float s2 = wred_sum(v.x * v.x + v.y * v.y + v.z * v.z + v.w * v.w);
  float mu = s1 * (1.f / 256.f);
  float inv = rsqrtf(s2 * (1.f / 256.f) - mu * mu + 1e-5f);
  float4 wv = *(const float4*)(w + lane * 4);
  float4 bv = *(const float4*)(b + lane * 4);
  float4 o;
  o.x = (v.x - mu) * inv * wv.x + bv.x;
  o.y = (v.y - mu) * inv * wv.y + bv.y;
  o.z = (v.z - mu) * inv * wv.z + bv.z;
  o.w = (v.w - mu) * inv * wv.w + bv.w;
  *(float4*)(y + (size_t)row * 256 + lane * 4) = o;
}

// ---------------------------------------------------------------------------
__global__ __launch_bounds__(64) void assemble_kernel(
    const float* __restrict__ coords, const float* __restrict__ cls,
    const float* __restrict__ pe, float* __restrict__ h) {
  const int i = blockIdx.x;
  const int lane = threadIdx.x;
  if (i == 0) {
    float4 c = *(const float4*)(cls + lane * 4);
    float4 p = *(const float4*)(pe + lane * 4);
    *(float4*)(h + lane * 4) =
        make_float4(c.x + p.x, c.y + p.y, c.z + p.z, c.w + p.w);
  } else {
    int g0 = (int)floorf(coords[(size_t)(i - 1) * 2 + 0] * (1.f / 256.f));
    int g1 = (int)floorf(coords[(size_t)(i - 1) * 2 + 1] * (1.f / 256.f));
    int pos = g0 * 512 + g1 + 1;
    float4 p = *(const float4*)(pe + (size_t)pos * 256 + lane * 4);
    float4 hv = *(const float4*)(h + (size_t)i * 256 + lane * 4);
    *(float4*)(h + (size_t)i * 256 + lane * 4) =
        make_float4(hv.x + p.x, hv.y + p.y, hv.z + p.z, hv.w + p.w);
  }
}

// ---------------------------------------------------------------------------
// Shared block decode for the 992 (unit, tile) blocks.
// ub = vt offset (elems) of this unit's [32][m] transposed-V panel.
// ---------------------------------------------------------------------------
__device__ __forceinline__ void decode_block(int bid, int& b, int& r, int& m,
                                             int& off, int& base, int& h,
                                             int& qt, int& ub) {
  if (bid < 512) {
    b = 0; r = 1; m = 1024; int u = bid >> 4; qt = bid & 15;
    base = (u >> 3) * 1024; h = u & 7; off = 0; ub = u * 32768;
  } else if (bid < 768) {
    b = 1; r = 2; m = 2048; int loc = bid - 512; h = loc >> 5; qt = loc & 31;
    base = 0; off = h & 1; ub = 1048576 + h * 65536;
  } else if (bid < 896) {
    b = 2; r = 4; m = 1024; int loc = bid - 768; h = loc >> 4; qt = loc & 15;
    base = 0; off = h & 3; ub = 1572864 + h * 32768;
  } else if (bid < 960) {
    b = 3; r = 8; m = 512; int loc = bid - 896; h = loc >> 3; qt = loc & 7;
    base = 0; off = h & 7; ub = 1835008 + h * 16384;
  } else {
    b = 4; r = 16; m = 256; int loc = bid - 960; h = loc >> 2; qt = loc & 3;
    base = 0; off = h; ub = 1966080 + h * 8192;
  }
}

// ---------------------------------------------------------------------------
// Gather V^T per (branch, unit): vt[unit][dim][key] bf16, key contiguous.
// Block = (unit, 64-key tile). LDS transpose.
// ---------------------------------------------------------------------------
__global__ __launch_bounds__(256) void vt_gather_kernel(
    const unsigned short* __restrict__ qkvb, unsigned short* __restrict__ vt) {
  __shared__ unsigned short T[32][64];
  int b, r, m, off, base, h, kt, ub;
  decode_block(blockIdx.x, b, r, m, off, base, h, kt, ub);
  const int t = threadIdx.x;
  {
    int key = t >> 2, fq = t & 3;
    size_t row = base + off + (size_t)r * (kt * 64 + key);
    short8 vv = *(const short8*)(qkvb + row * 768 + 512 + h * 32 + 8 * fq);
#pragma unroll
    for (int i = 0; i < 8; i++) T[8 * fq + i][key] = (unsigned short)vv[i];
  }
  __syncthreads();
  int dim = t >> 3, c8 = t & 7;
  *(short8*)(vt + ub + (size_t)dim * m + kt * 64 + c8 * 8) =
      *(const short8*)&T[dim][c8 * 8];
}

// ---------------------------------------------------------------------------
// bf16 MFMA flash attention, LDS-free. 992 blocks, 4 waves, 16 q-rows/wave.
// Swapped QK^T: st = mfma(K_frag, Q_frag) -> S^T; lane holds col q=lane&15,
// keys 16a+4g+reg. Online softmax in-register. P^T re-fragmented via
// cvt_pk_bf16 + bpermute into the PV B-operand. PV: O^T = Vt . P^T.
// ---------------------------------------------------------------------------
__global__ __launch_bounds__(256) void attn_mfma_kernel(
    const unsigned short* __restrict__ qkvb,
    const unsigned short* __restrict__ vt, float* __restrict__ out_all,
    float* __restrict__ lse_all) {
  int b, r, m, off, base, h, qt, ub;
  decode_block(blockIdx.x, b, r, m, off, base, h, qt, ub);

  const int lane = threadIdx.x & 63;
  const int wid = threadIdx.x >> 6;
  const int g = lane >> 4, q = lane & 15;
  const int q0 = qt * 64 + wid * 16;

  const size_t qrow = base + off + (size_t)r * (q0 + q);
  short8 qf = *(const short8*)(qkvb + qrow * 768 + h * 32 + 8 * g);

  f32x4 ot0 = {0.f, 0.f, 0.f, 0.f}, ot1 = {0.f, 0.f, 0.f, 0.f};
  float rm = -1e30f, rl = 0.f;
  const float scale = 0.17677669529663687f;  // 1/sqrt(32)
  const int ntiles = m >> 6;

  for (int kt = 0; kt < ntiles; ++kt) {
    const int k0 = kt * 64;
    f32x4 st[4];
#pragma unroll
    for (int a = 0; a < 4; a++) {
      int krow = base + off + r * (k0 + 16 * a + q);
      short8 kf =
          *(const short8*)(qkvb + (size_t)krow * 768 + 256 + h * 32 + 8 * g);
      f32x4 z = {0.f, 0.f, 0.f, 0.f};
      st[a] = __builtin_amdgcn_mfma_f32_16x16x32_bf16(kf, qf, z, 0, 0, 0);
    }
    float p[4][4];
    float mx = -1e30f;
#pragma unroll
    for (int a = 0; a < 4; a++)
#pragma unroll
      for (int rr = 0; rr < 4; rr++) {
        p[a][rr] = st[a][rr] * scale;
        mx = fmaxf(mx, p[a][rr]);
      }
    mx = fmaxf(mx, __shfl_xor(mx, 16));
    mx = fmaxf(mx, __shfl_xor(mx, 32));
    float nm = fmaxf(rm, mx);
    float corr = __expf(rm - nm);
    float tl = 0.f;
#pragma unroll
    for (int a = 0; a < 4; a++)
#pragma unroll
      for (int rr = 0; rr < 4; rr++) {
        p[a][rr] = __expf(p[a][rr] - nm);
        tl += p[a][rr];
      }
    tl += __shfl_xor(tl, 16);
    tl += __shfl_xor(tl, 32);
    rl = rl * corr + tl;
    rm = nm;
    ot0 *= corr;
    ot1 *= corr;

    unsigned pk[4][2];
#pragma unroll
    for (int a = 0; a < 4; a++) {
      asm("v_cvt_pk_bf16_f32 %0, %1, %2"
          : "=v"(pk[a][0]) : "v"(p[a][0]), "v"(p[a][1]));
      asm("v_cvt_pk_bf16_f32 %0, %1, %2"
          : "=v"(pk[a][1]) : "v"(p[a][2]), "v"(p[a][3]));
    }

#pragma unroll
    for (int kk = 0; kk < 2; kk++) {
      union { unsigned w[4]; short8 v; } pb;
#pragma unroll
      for (int jj = 0; jj < 2; jj++) {
        int src = q + 16 * ((2 * g + jj) & 3);
#pragma unroll
        for (int d = 0; d < 2; d++) {
          unsigned lo = (unsigned)__shfl((int)pk[2 * kk + 0][d], src);
          unsigned hi = (unsigned)__shfl((int)pk[2 * kk + 1][d], src);
          pb.w[jj * 2 + d] = (g >> 1) ? hi : lo;
        }
      }
      const unsigned short* vp = vt + ub + (size_t)q * m + k0 + 32 * kk + 8 * g;
      short8 v0 = *(const short8*)(vp);
      short8 v1 = *(const short8*)(vp + (size_t)16 * m);
      ot0 = __builtin_amdgcn_mfma_f32_16x16x32_bf16(v0, pb.v, ot0, 0, 0, 0);
      ot1 = __builtin_amdgcn_mfma_f32_16x16x32_bf16(v1, pb.v, ot1, 0, 0, 0);
    }
  }

  float inv = 1.f / rl;
  int pos = base + off + r * (q0 + q);
  size_t ob = (((size_t)b * 4096 + pos) * 8 + h) * 32;
  f32x4 o0 = ot0 * inv, o1 = ot1 * inv;
  *(f32x4*)(out_all + ob + 4 * g) = o0;
  *(f32x4*)(out_all + ob + 16 + 4 * g) = o1;
  if (g == 0)
    lse_all[((size_t)b * 4096 + pos) * 8 + h] = rm + __logf(rl);
}

// ---------------------------------------------------------------------------
// Combine the 5 branch outputs per (pos, head) by LSE softmax weighting.
// ---------------------------------------------------------------------------
__global__ __launch_bounds__(256) void combine_kernel(
    const float* __restrict__ out_all, const float* __restrict__ lse_all,
    float* __restrict__ att) {
  const int tid = blockIdx.x * 256 + threadIdx.x;
  const int pos = tid >> 8;
  const int ph = (tid >> 5) & 7;
  const int d = tid & 31;

  float lse[5];
  bool cov[5];
#pragma unroll
  for (int b = 0; b < 5; b++) {
    int rr = 1 << b;
    cov[b] = ((pos ^ ph) & (rr - 1)) == 0;
    lse[b] = cov[b] ? lse_all[((size_t)b * 4096 + pos) * 8 + ph] : -3.0e38f;
  }
  float mx = lse[0];
#pragma unroll
  for (int b = 1; b < 5; b++) mx = fmaxf(mx, lse[b]);
  float wsum = 0.f, o = 0.f;
#pragma unroll
  for (int b = 0; b < 5; b++) {
    if (cov[b]) {
      float w = __expf(lse[b] - mx);
      wsum += w;
      o += w * out_all[(((size_t)b * 4096 + pos) * 8 + ph) * 32 + d];
    }
  }
  att[(size_t)pos * 256 + ph * 32 + d] = o / wsum;
}

// ---------------------------------------------------------------------------
__global__ __launch_bounds__(64) void final_kernel(
    const float* __restrict__ h, const float* __restrict__ ew,
    const float* __restrict__ eb, const float* __restrict__ nw,
    const float* __restrict__ nb, float* __restrict__ out) {
  const int lane = threadIdx.x;
  float4 v = *(const float4*)(h + lane * 4);
  float s1 = wred_sum(v.x + v.y + v.z + v.w);
  float s2 = wred_sum(v.x * v.x + v.y * v.y + v.z * v.z + v.w * v.w);
  float mu = s1 * (1.f / 256.f);
  float inv = rsqrtf(s2 * (1.f / 256.f) - mu * mu + 1e-5f);
  float4 wv = *(const float4*)(ew + lane * 4);
  float4 bv = *(const float4*)(eb + lane * 4);
  float4 tv;
  tv.x = (v.x - mu) * inv * wv.x + bv.x;
  tv.y = (v.y - mu) * inv * wv.y + bv.y;
  tv.z = (v.z - mu) * inv * wv.z + bv.z;
  tv.w = (v.w - mu) * inv * wv.w + bv.w;
  s1 = wred_sum(tv.x + tv.y + tv.z + tv.w);
  s2 = wred_sum(tv.x * tv.x + tv.y * tv.y + tv.z * tv.z + tv.w * tv.w);
  mu = s1 * (1.f / 256.f);
  inv = rsqrtf(s2 * (1.f / 256.f) - mu * mu + 1e-5f);
  float4 w2v = *(const float4*)(nw + lane * 4);
  float4 b2v = *(const float4*)(nb + lane * 4);
  float4 o;
  o.x = (tv.x - mu) * inv * w2v.x + b2v.x;
  o.y = (tv.y - mu) * inv * w2v.y + b2v.y;
  o.z = (tv.z - mu) * inv * w2v.z + b2v.z;
  o.w = (tv.w - mu) * inv * w2v.w + b2v.w;
  *(float4*)(out + lane * 4) = o;
}

// ---------------------------------------------------------------------------

extern "C" void kernel_launch(void* const* d_in, const int* in_sizes, int n_in,
                              void* d_out, int out_size, void* d_ws,
                              size_t ws_size, hipStream_t stream) {
  const float* x      = (const float*)d_in[0];
  const float* coords = (const float*)d_in[1];
  const float* pw     = (const float*)d_in[2];
  const float* pb     = (const float*)d_in[3];
  const float* cls    = (const float*)d_in[4];
  const float* pe     = (const float*)d_in[5];
  const float* ln1w   = (const float*)d_in[6];
  const float* ln1b   = (const float*)d_in[7];
  const float* wqkv   = (const float*)d_in[8];
  const float* bqkv   = (const float*)d_in[9];
  const float* wo     = (const float*)d_in[10];
  const float* bo     = (const float*)d_in[11];
  const float* ln2w   = (const float*)d_in[12];
  const float* ln2b   = (const float*)d_in[13];
  const float* w1     = (const float*)d_in[14];
  const float* b1     = (const float*)d_in[15];
  const float* w2     = (const float*)d_in[16];
  const float* b2     = (const float*)d_in[17];
  const float* encw   = (const float*)d_in[18];
  const float* encb   = (const float*)d_in[19];
  const float* nw     = (const float*)d_in[20];
  const float* nb     = (const float*)d_in[21];

  float* ws = (float*)d_ws;
  float* h             = ws;                       // 1,048,576 f32
  float* hn            = h + 1048576;              // 1,048,576 f32
  unsigned short* qkvb = (unsigned short*)(hn + 1048576);  // 3,145,728 bf16
  float* out_all       = hn + 1048576 + 1572864;   // 5,242,880 f32
  float* lse           = out_all + 5242880;        //   163,840 (pad 262,144)
  float* att           = lse + 262144;             // 1,048,576 f32
  float* mid           = att + 1048576;            // 4,194,304 f32
  unsigned short* vt   = (unsigned short*)(mid + 4194304);  // 2,031,616 bf16
  // total ~15.47M floats ~= 62 MiB

  gemm_kernel<0><<<dim3(64, 4), 256, 0, stream>>>(x, pw, pb, h + 256, 4095, 256, 1536);
  assemble_kernel<<<4096, 64, 0, stream>>>(coords, cls, pe, h);

  for (int l = 0; l < 4; l++) {
    ln_kernel<<<1024, 256, 0, stream>>>(h, ln1w + l * 256, ln1b + l * 256, hn);
    gemm_kernel<3><<<dim3(64, 12), 256, 0, stream>>>(
        hn, wqkv + (size_t)l * 196608, bqkv + l * 768, qkvb, 4096, 768, 256);
    vt_gather_kernel<<<992, 256, 0, stream>>>(qkvb, vt);
    attn_mfma_kernel<<<992, 256, 0, stream>>>(qkvb, vt, out_all, lse);
    combine_kernel<<<4096, 256, 0, stream>>>(out_all, lse, att);
    gemm_kernel<2><<<dim3(64, 4), 256, 0, stream>>>(
        att, wo + (size_t)l * 65536, bo + l * 256, h, 4096, 256, 256);
    ln_kernel<<<1024, 256, 0, stream>>>(h, ln2w + l * 256, ln2b + l * 256, hn);
    gemm_kernel<1><<<dim3(64, 16), 256, 0, stream>>>(
        hn, w1 + (size_t)l * 262144, b1 + l * 1024, mid, 4096, 1024, 256);
    gemm_kernel<2><<<dim3(64, 4), 256, 0, stream>>>(
        mid, w2 + (size_t)l * 262144, b2 + l * 256, h, 4096, 256, 1024);
  }

  final_kernel<<<1, 64, 0, stream>>>(h, encw, encb, nw, nb, (float*)d_out);
}

// Round 3
// 727.064 us; speedup vs baseline: 5.2918x; 1.4890x over previous
//
#include <hip/hip_runtime.h>
#include <hip/hip_bf16.h>
#include <math.h>

// ---------------------------------------------------------------------------
// LongNetViT forward. L=4096 (cls+4095), D=256, H=8, HD=32, DEPTH=4.
// bf16 MFMA everywhere (fp32 accumulate, fp32 residual stream).
// Branches at L=4096: b0 r=1 m=1024 segs=4 | b1 r=2 m=2048 | b2 r=4 m=1024
//                     b3 r=8 m=512 | b4 r=16 m=256   (no padding)
// ---------------------------------------------------------------------------

typedef __attribute__((ext_vector_type(8))) short short8;
typedef __attribute__((ext_vector_type(4))) float f32x4;

__device__ __forceinline__ float wred_sum(float v) {
#pragma unroll
  for (int o = 32; o; o >>= 1) v += __shfl_xor(v, o);
  return v;
}

__device__ __forceinline__ unsigned short f2bf(float x) {
  unsigned u = __float_as_uint(x);
  u += 0x7FFF + ((u >> 16) & 1);
  return (unsigned short)(u >> 16);
}

// ---------------------------------------------------------------------------
// bf16 MFMA GEMM, zero-LDS. C[M,N] = epi(A[M,K]bf16 @ Bt[N,K]bf16^T + bias).
// Block 256 thr = 4 waves; tile 64(M)x64(N); wave w owns rows [16w,16w+16),
// all 64 cols (4 col-frags). EPI: 0 = f32 out, 1 = GELU -> bf16 out,
// 2 = residual add into f32 C, 3 = bf16 out.
// ---------------------------------------------------------------------------
template <int EPI>
__global__ __launch_bounds__(256) void gemm_bf16(
    const unsigned short* __restrict__ A, const unsigned short* __restrict__ Bt,
    const float* __restrict__ bias, void* __restrict__ Cv, int M, int N,
    int K) {
  const int lane = threadIdx.x & 63, w = threadIdx.x >> 6;
  const int g = lane >> 4, q = lane & 15;
  const int bm = blockIdx.x * 64, bn = blockIdx.y * 64;

  int arow = bm + 16 * w + q;
  int ar = arow < M ? arow : M - 1;
  const unsigned short* ap = A + (size_t)ar * K + 8 * g;
  const unsigned short* bp = Bt + (size_t)(bn + q) * K + 8 * g;

  f32x4 acc[4];
#pragma unroll
  for (int i = 0; i < 4; i++) acc[i] = (f32x4){0.f, 0.f, 0.f, 0.f};

#pragma unroll 2
  for (int k0 = 0; k0 < K; k0 += 32) {
    short8 af = *(const short8*)(ap + k0);
#pragma unroll
    for (int cf = 0; cf < 4; cf++) {
      short8 bf = *(const short8*)(bp + (size_t)(16 * cf) * K + k0);
      acc[cf] = __builtin_amdgcn_mfma_f32_16x16x32_bf16(af, bf, acc[cf], 0, 0, 0);
    }
  }

  const int orow0 = bm + 16 * w + 4 * g;
#pragma unroll
  for (int cf = 0; cf < 4; cf++) {
    const int col = bn + 16 * cf + q;
    const float bs = bias[col];
#pragma unroll
    for (int rg = 0; rg < 4; rg++) {
      int orow = orow0 + rg;
      if (orow < M) {
        float c = acc[cf][rg] + bs;
        size_t idx = (size_t)orow * N + col;
        if (EPI == 1) {
          c = 0.5f * c * (1.f + erff(c * 0.70710678118654752f));
          ((unsigned short*)Cv)[idx] = f2bf(c);
        } else if (EPI == 3) {
          ((unsigned short*)Cv)[idx] = f2bf(c);
        } else if (EPI == 2) {
          float* p = (float*)Cv;
          p[idx] += c;
        } else {
          ((float*)Cv)[idx] = c;
        }
      }
    }
  }
}

// ---------------------------------------------------------------------------
// One-shot prepass: transpose+convert all weights to Bt[N][K] bf16.
// Flat grid of 32x32 tiles over 17 tensors (offsets hardcoded).
// ---------------------------------------------------------------------------
__global__ __launch_bounds__(256) void wtrans_kernel(
    const float* __restrict__ pw, const float* __restrict__ wqkv,
    const float* __restrict__ wo, const float* __restrict__ w1,
    const float* __restrict__ w2, unsigned short* __restrict__ wt) {
  __shared__ float T[32][33];
  const int bid = blockIdx.x;
  const float* src;
  int Kd, Nd, lt;
  size_t doff;
  if (bid < 384) {
    src = pw; Kd = 1536; Nd = 256; doff = 0; lt = bid;
  } else if (bid < 1152) {
    int l = (bid - 384) / 192, r = (bid - 384) % 192;
    src = wqkv + (size_t)l * 196608; Kd = 256; Nd = 768;
    doff = 393216 + (size_t)l * 196608; lt = r;
  } else if (bid < 1408) {
    int l = (bid - 1152) / 64, r = (bid - 1152) % 64;
    src = wo + (size_t)l * 65536; Kd = 256; Nd = 256;
    doff = 1179648 + (size_t)l * 65536; lt = r;
  } else if (bid < 2432) {
    int l = (bid - 1408) / 256, r = (bid - 1408) % 256;
    src = w1 + (size_t)l * 262144; Kd = 256; Nd = 1024;
    doff = 1441792 + (size_t)l * 262144; lt = r;
  } else {
    int l = (bid - 2432) / 256, r = (bid - 2432) % 256;
    src = w2 + (size_t)l * 262144; Kd = 1024; Nd = 256;
    doff = 2490368 + (size_t)l * 262144; lt = r;
  }
  const int tilesK = Kd >> 5;
  const int tn = lt / tilesK, tk = lt % tilesK;
  const int k0 = tk * 32, n0 = tn * 32;
  const int t = threadIdx.x;
  const int rr = t >> 3, c4 = t & 7;
  float4 v = *(const float4*)(src + (size_t)(k0 + rr) * Nd + n0 + c4 * 4);
  T[rr][c4 * 4 + 0] = v.x;
  T[rr][c4 * 4 + 1] = v.y;
  T[rr][c4 * 4 + 2] = v.z;
  T[rr][c4 * 4 + 3] = v.w;
  __syncthreads();
  float o0 = T[c4 * 4 + 0][rr], o1 = T[c4 * 4 + 1][rr];
  float o2 = T[c4 * 4 + 2][rr], o3 = T[c4 * 4 + 3][rr];
  unsigned u0 = (unsigned)f2bf(o0) | ((unsigned)f2bf(o1) << 16);
  unsigned u1 = (unsigned)f2bf(o2) | ((unsigned)f2bf(o3) << 16);
  *(uint2*)(wt + doff + (size_t)(n0 + rr) * Kd + k0 + c4 * 4) =
      make_uint2(u0, u1);
}

// ---------------------------------------------------------------------------
// x (4095*1536 f32) -> bf16.
// ---------------------------------------------------------------------------
__global__ __launch_bounds__(256) void convx_kernel(
    const float* __restrict__ x, unsigned short* __restrict__ xb) {
  const int i = blockIdx.x * 256 + threadIdx.x;
  if (i >= 786240) return;  // 6289920 / 8
  const float4 a = *(const float4*)(x + (size_t)i * 8);
  const float4 b = *(const float4*)(x + (size_t)i * 8 + 4);
  unsigned u0 = (unsigned)f2bf(a.x) | ((unsigned)f2bf(a.y) << 16);
  unsigned u1 = (unsigned)f2bf(a.z) | ((unsigned)f2bf(a.w) << 16);
  unsigned u2 = (unsigned)f2bf(b.x) | ((unsigned)f2bf(b.y) << 16);
  unsigned u3 = (unsigned)f2bf(b.z) | ((unsigned)f2bf(b.w) << 16);
  *(uint4*)(xb + (size_t)i * 8) = make_uint4(u0, u1, u2, u3);
}

// ---------------------------------------------------------------------------
// LayerNorm over D=256, bf16 out; one wave per row, 4 rows per block.
// ---------------------------------------------------------------------------
__global__ __launch_bounds__(256) void ln_bf16_kernel(
    const float* __restrict__ x, const float* __restrict__ w,
    const float* __restrict__ b, unsigned short* __restrict__ y) {
  const int row = blockIdx.x * 4 + (threadIdx.x >> 6);
  const int lane = threadIdx.x & 63;
  float4 v = *(const float4*)(x + (size_t)row * 256 + lane * 4);
  float s1 = wred_sum(v.x + v.y + v.z + v.w);
  float s2 = wred_sum(v.x * v.x + v.y * v.y + v.z * v.z + v.w * v.w);
  float mu = s1 * (1.f / 256.f);
  float inv = rsqrtf(s2 * (1.f / 256.f) - mu * mu + 1e-5f);
  float4 wv = *(const float4*)(w + lane * 4);
  float4 bv = *(const float4*)(b + lane * 4);
  float o0 = (v.x - mu) * inv * wv.x + bv.x;
  float o1 = (v.y - mu) * inv * wv.y + bv.y;
  float o2 = (v.z - mu) * inv * wv.z + bv.z;
  float o3 = (v.w - mu) * inv * wv.w + bv.w;
  unsigned u0 = (unsigned)f2bf(o0) | ((unsigned)f2bf(o1) << 16);
  unsigned u1 = (unsigned)f2bf(o2) | ((unsigned)f2bf(o3) << 16);
  *(uint2*)(y + (size_t)row * 256 + lane * 4) = make_uint2(u0, u1);
}

// ---------------------------------------------------------------------------
__global__ __launch_bounds__(64) void assemble_kernel(
    const float* __restrict__ coords, const float* __restrict__ cls,
    const float* __restrict__ pe, float* __restrict__ h) {
  const int i = blockIdx.x;
  const int lane = threadIdx.x;
  if (i == 0) {
    float4 c = *(const float4*)(cls + lane * 4);
    float4 p = *(const float4*)(pe + lane * 4);
    *(float4*)(h + lane * 4) =
        make_float4(c.x + p.x, c.y + p.y, c.z + p.z, c.w + p.w);
  } else {
    int g0 = (int)floorf(coords[(size_t)(i - 1) * 2 + 0] * (1.f / 256.f));
    int g1 = (int)floorf(coords[(size_t)(i - 1) * 2 + 1] * (1.f / 256.f));
    int pos = g0 * 512 + g1 + 1;
    float4 p = *(const float4*)(pe + (size_t)pos * 256 + lane * 4);
    float4 hv = *(const float4*)(h + (size_t)i * 256 + lane * 4);
    *(float4*)(h + (size_t)i * 256 + lane * 4) =
        make_float4(hv.x + p.x, hv.y + p.y, hv.z + p.z, hv.w + p.w);
  }
}

// ---------------------------------------------------------------------------
// Shared block decode for the 992 (unit, tile) blocks.
// ub = elem offset of this unit's panel in kg ([m][32]) and vt ([32][m]).
// ---------------------------------------------------------------------------
__device__ __forceinline__ void decode_block(int bid, int& b, int& r, int& m,
                                             int& off, int& base, int& h,
                                             int& qt, int& ub) {
  if (bid < 512) {
    b = 0; r = 1; m = 1024; int u = bid >> 4; qt = bid & 15;
    base = (u >> 3) * 1024; h = u & 7; off = 0; ub = u * 32768;
  } else if (bid < 768) {
    b = 1; r = 2; m = 2048; int loc = bid - 512; h = loc >> 5; qt = loc & 31;
    base = 0; off = h & 1; ub = 1048576 + h * 65536;
  } else if (bid < 896) {
    b = 2; r = 4; m = 1024; int loc = bid - 768; h = loc >> 4; qt = loc & 15;
    base = 0; off = h & 3; ub = 1572864 + h * 32768;
  } else if (bid < 960) {
    b = 3; r = 8; m = 512; int loc = bid - 896; h = loc >> 3; qt = loc & 7;
    base = 0; off = h & 7; ub = 1835008 + h * 16384;
  } else {
    b = 4; r = 16; m = 256; int loc = bid - 960; h = loc >> 2; qt = loc & 3;
    base = 0; off = h; ub = 1966080 + h * 8192;
  }
}

// ---------------------------------------------------------------------------
// Gather K panels kg[unit][key][32] and V^T panels vt[unit][dim][key].
// Block = (unit, 64-key tile).
// ---------------------------------------------------------------------------
__global__ __launch_bounds__(256) void gather_kernel(
    const unsigned short* __restrict__ qkvb, unsigned short* __restrict__ kg,
    unsigned short* __restrict__ vt) {
  __shared__ unsigned short T[32][64];
  int b, r, m, off, base, h, kt, ub;
  decode_block(blockIdx.x, b, r, m, off, base, h, kt, ub);
  const int t = threadIdx.x;
  {
    int key = t >> 2, c = t & 3;
    size_t row = base + off + (size_t)r * (kt * 64 + key);
    const unsigned short* src = qkvb + row * 768 + h * 32 + 8 * c;
    short8 kk = *(const short8*)(src + 256);
    *(short8*)(kg + ub + (size_t)(kt * 64 + key) * 32 + 8 * c) = kk;
    short8 vv = *(const short8*)(src + 512);
#pragma unroll
    for (int i = 0; i < 8; i++) T[8 * c + i][key] = (unsigned short)vv[i];
  }
  __syncthreads();
  int dim = t >> 3, c8 = t & 7;
  *(short8*)(vt + ub + (size_t)dim * m + kt * 64 + 8 * c8) =
      *(const short8*)&T[dim][8 * c8];
}

// ---------------------------------------------------------------------------
// bf16 MFMA flash attention, LDS-free, all operands coalesced.
// 992 blocks, 4 waves, 16 q-rows/wave. Swapped QK^T -> S^T; online softmax
// in-register; P^T re-fragmented via cvt_pk_bf16 + shfl; PV: O^T = Vt . P^T.
// ---------------------------------------------------------------------------
__global__ __launch_bounds__(256) void attn_mfma_kernel(
    const unsigned short* __restrict__ qkvb,
    const unsigned short* __restrict__ kg, const unsigned short* __restrict__ vt,
    float* __restrict__ out_all, float* __restrict__ lse_all) {
  int b, r, m, off, base, h, qt, ub;
  decode_block(blockIdx.x, b, r, m, off, base, h, qt, ub);

  const int lane = threadIdx.x & 63;
  const int wid = threadIdx.x >> 6;
  const int g = lane >> 4, q = lane & 15;
  const int q0 = qt * 64 + wid * 16;

  const size_t qrow = base + off + (size_t)r * (q0 + q);
  short8 qf = *(const short8*)(qkvb + qrow * 768 + h * 32 + 8 * g);

  f32x4 ot0 = {0.f, 0.f, 0.f, 0.f}, ot1 = {0.f, 0.f, 0.f, 0.f};
  float rm = -1e30f, rl = 0.f;
  const float scale = 0.17677669529663687f;  // 1/sqrt(32)
  const int ntiles = m >> 6;

  for (int kt = 0; kt < ntiles; ++kt) {
    const int k0 = kt * 64;
    f32x4 st[4];
#pragma unroll
    for (int a = 0; a < 4; a++) {
      short8 kf = *(const short8*)(kg + ub + (size_t)(k0 + 16 * a) * 32 +
                                   (size_t)q * 32 + 8 * g);
      f32x4 z = {0.f, 0.f, 0.f, 0.f};
      st[a] = __builtin_amdgcn_mfma_f32_16x16x32_bf16(kf, qf, z, 0, 0, 0);
    }
    float p[4][4];
    float mx = -1e30f;
#pragma unroll
    for (int a = 0; a < 4; a++)
#pragma unroll
      for (int rr = 0; rr < 4; rr++) {
        p[a][rr] = st[a][rr] * scale;
        mx = fmaxf(mx, p[a][rr]);
      }
    mx = fmaxf(mx, __shfl_xor(mx, 16));
    mx = fmaxf(mx, __shfl_xor(mx, 32));
    float nm = fmaxf(rm, mx);
    float corr = __expf(rm - nm);
    float tl = 0.f;
#pragma unroll
    for (int a = 0; a < 4; a++)
#pragma unroll
      for (int rr = 0; rr < 4; rr++) {
        p[a][rr] = __expf(p[a][rr] - nm);
        tl += p[a][rr];
      }
    tl += __shfl_xor(tl, 16);
    tl += __shfl_xor(tl, 32);
    rl = rl * corr + tl;
    rm = nm;
    ot0 *= corr;
    ot1 *= corr;

    unsigned pk[4][2];
#pragma unroll
    for (int a = 0; a < 4; a++) {
      asm("v_cvt_pk_bf16_f32 %0, %1, %2"
          : "=v"(pk[a][0]) : "v"(p[a][0]), "v"(p[a][1]));
      asm("v_cvt_pk_bf16_f32 %0, %1, %2"
          : "=v"(pk[a][1]) : "v"(p[a][2]), "v"(p[a][3]));
    }

#pragma unroll
    for (int kk = 0; kk < 2; kk++) {
      union { unsigned w[4]; short8 v; } pb;
#pragma unroll
      for (int jj = 0; jj < 2; jj++) {
        int src = q + 16 * ((2 * g + jj) & 3);
#pragma unroll
        for (int d = 0; d < 2; d++) {
          unsigned lo = (unsigned)__shfl((int)pk[2 * kk + 0][d], src);
          unsigned hi = (unsigned)__shfl((int)pk[2 * kk + 1][d], src);
          pb.w[jj * 2 + d] = (g >> 1) ? hi : lo;
        }
      }
      const unsigned short* vp = vt + ub + (size_t)q * m + k0 + 32 * kk + 8 * g;
      short8 v0 = *(const short8*)(vp);
      short8 v1 = *(const short8*)(vp + (size_t)16 * m);
      ot0 = __builtin_amdgcn_mfma_f32_16x16x32_bf16(v0, pb.v, ot0, 0, 0, 0);
      ot1 = __builtin_amdgcn_mfma_f32_16x16x32_bf16(v1, pb.v, ot1, 0, 0, 0);
    }
  }

  float inv = 1.f / rl;
  int pos = base + off + r * (q0 + q);
  size_t ob = (((size_t)b * 4096 + pos) * 8 + h) * 32;
  f32x4 o0 = ot0 * inv, o1 = ot1 * inv;
  *(f32x4*)(out_all + ob + 4 * g) = o0;
  *(f32x4*)(out_all + ob + 16 + 4 * g) = o1;
  if (g == 0)
    lse_all[((size_t)b * 4096 + pos) * 8 + h] = rm + __logf(rl);
}

// ---------------------------------------------------------------------------
// Combine 5 branch outputs per (pos, head) by LSE softmax; bf16 out.
// Branch b covers (pos,h) iff (pos ^ h) & (r_b - 1) == 0.
// ---------------------------------------------------------------------------
__global__ __launch_bounds__(256) void combine_kernel(
    const float* __restrict__ out_all, const float* __restrict__ lse_all,
    unsigned short* __restrict__ att) {
  const int tid = blockIdx.x * 256 + threadIdx.x;  // 524288 total
  const int pos = tid >> 7;
  const int ph = (tid >> 4) & 7;
  const int d0 = (tid & 15) * 2;

  float lse[5];
  bool cov[5];
#pragma unroll
  for (int b = 0; b < 5; b++) {
    int rr = 1 << b;
    cov[b] = ((pos ^ ph) & (rr - 1)) == 0;
    lse[b] = cov[b] ? lse_all[((size_t)b * 4096 + pos) * 8 + ph] : -3.0e38f;
  }
  float mx = lse[0];
#pragma unroll
  for (int b = 1; b < 5; b++) mx = fmaxf(mx, lse[b]);
  float wsum = 0.f, o0 = 0.f, o1 = 0.f;
#pragma unroll
  for (int b = 0; b < 5; b++) {
    if (cov[b]) {
      float w = __expf(lse[b] - mx);
      wsum += w;
      float2 v =
          *(const float2*)(out_all + (((size_t)b * 4096 + pos) * 8 + ph) * 32 + d0);
      o0 += w * v.x;
      o1 += w * v.y;
    }
  }
  float inv = 1.f / wsum;
  unsigned u = (unsigned)f2bf(o0 * inv) | ((unsigned)f2bf(o1 * inv) << 16);
  *(unsigned*)(att + (size_t)pos * 256 + ph * 32 + d0) = u;
}

// ---------------------------------------------------------------------------
__global__ __launch_bounds__(64) void final_kernel(
    const float* __restrict__ h, const float* __restrict__ ew,
    const float* __restrict__ eb, const float* __restrict__ nw,
    const float* __restrict__ nb, float* __restrict__ out) {
  const int lane = threadIdx.x;
  float4 v = *(const float4*)(h + lane * 4);
  float s1 = wred_sum(v.x + v.y + v.z + v.w);
  float s2 = wred_sum(v.x * v.x + v.y * v.y + v.z * v.z + v.w * v.w);
  float mu = s1 * (1.f / 256.f);
  float inv = rsqrtf(s2 * (1.f / 256.f) - mu * mu + 1e-5f);
  float4 wv = *(const float4*)(ew + lane * 4);
  float4 bv = *(const float4*)(eb + lane * 4);
  float4 tv;
  tv.x = (v.x - mu) * inv * wv.x + bv.x;
  tv.y = (v.y - mu) * inv * wv.y + bv.y;
  tv.z = (v.z - mu) * inv * wv.z + bv.z;
  tv.w = (v.w - mu) * inv * wv.w + bv.w;
  s1 = wred_sum(tv.x + tv.y + tv.z + tv.w);
  s2 = wred_sum(tv.x * tv.x + tv.y * tv.y + tv.z * tv.z + tv.w * tv.w);
  mu = s1 * (1.f / 256.f);
  inv = rsqrtf(s2 * (1.f / 256.f) - mu * mu + 1e-5f);
  float4 w2v = *(const float4*)(nw + lane * 4);
  float4 b2v = *(const float4*)(nb + lane * 4);
  float4 o;
  o.x = (tv.x - mu) * inv * w2v.x + b2v.x;
  o.y = (tv.y - mu) * inv * w2v.y + b2v.y;
  o.z = (tv.z - mu) * inv * w2v.z + b2v.z;
  o.w = (tv.w - mu) * inv * w2v.w + b2v.w;
  *(float4*)(out + lane * 4) = o;
}

// ---------------------------------------------------------------------------

extern "C" void kernel_launch(void* const* d_in, const int* in_sizes, int n_in,
                              void* d_out, int out_size, void* d_ws,
                              size_t ws_size, hipStream_t stream) {
  const float* x      = (const float*)d_in[0];
  const float* coords = (const float*)d_in[1];
  const float* pw     = (const float*)d_in[2];
  const float* pb     = (const float*)d_in[3];
  const float* cls    = (const float*)d_in[4];
  const float* pe     = (const float*)d_in[5];
  const float* ln1w   = (const float*)d_in[6];
  const float* ln1b   = (const float*)d_in[7];
  const float* wqkv   = (const float*)d_in[8];
  const float* bqkv   = (const float*)d_in[9];
  const float* wo     = (const float*)d_in[10];
  const float* bo     = (const float*)d_in[11];
  const float* ln2w   = (const float*)d_in[12];
  const float* ln2b   = (const float*)d_in[13];
  const float* w1     = (const float*)d_in[14];
  const float* b1     = (const float*)d_in[15];
  const float* w2     = (const float*)d_in[16];
  const float* b2     = (const float*)d_in[17];
  const float* encw   = (const float*)d_in[18];
  const float* encb   = (const float*)d_in[19];
  const float* nw     = (const float*)d_in[20];
  const float* nb     = (const float*)d_in[21];

  float* ws = (float*)d_ws;
  float* h              = ws;                                   // [0, 1048576)
  unsigned short* hnb   = (unsigned short*)(ws + 1048576);      // 1,048,576 us
  unsigned short* qkvb  = (unsigned short*)(ws + 1310720);      // 3,145,728 us
  unsigned short* kg    = (unsigned short*)(ws + 2883584);      // 2,031,616 us
  unsigned short* vt    = (unsigned short*)(ws + 3899392);      // 2,031,616 us
  float* out_all        = ws + 4915200;                         // 5,242,880 f32
  float* lse            = ws + 10158080;                        //   163,840 f32
  unsigned short* attb  = (unsigned short*)(ws + 10321920);     // 1,048,576 us
  unsigned short* midb  = (unsigned short*)(ws + 10846208);     // 4,194,304 us
  unsigned short* xb    = (unsigned short*)(ws + 12943360);     // 6,289,920 us
  unsigned short* wt    = (unsigned short*)(ws + 16088320);     // 3,538,944 us
  // total ~17.9M f32 slots ~= 71.4 MiB

  // ---- prepass (every call; deterministic) ----
  convx_kernel<<<3072, 256, 0, stream>>>(x, xb);
  wtrans_kernel<<<3456, 256, 0, stream>>>(pw, wqkv, wo, w1, w2, wt);

  // patch embed (bf16 MFMA) -> h rows 1..4095 (f32 out)
  gemm_bf16<0><<<dim3(64, 4), 256, 0, stream>>>(xb, wt, pb, h + 256, 4095, 256,
                                                1536);
  assemble_kernel<<<4096, 64, 0, stream>>>(coords, cls, pe, h);

  for (int l = 0; l < 4; l++) {
    ln_bf16_kernel<<<1024, 256, 0, stream>>>(h, ln1w + l * 256, ln1b + l * 256,
                                             hnb);
    gemm_bf16<3><<<dim3(64, 12), 256, 0, stream>>>(
        hnb, wt + 393216 + (size_t)l * 196608, bqkv + l * 768, qkvb, 4096, 768,
        256);
    gather_kernel<<<992, 256, 0, stream>>>(qkvb, kg, vt);
    attn_mfma_kernel<<<992, 256, 0, stream>>>(qkvb, kg, vt, out_all, lse);
    combine_kernel<<<2048, 256, 0, stream>>>(out_all, lse, attb);
    gemm_bf16<2><<<dim3(64, 4), 256, 0, stream>>>(
        attb, wt + 1179648 + (size_t)l * 65536, bo + l * 256, h, 4096, 256,
        256);
    ln_bf16_kernel<<<1024, 256, 0, stream>>>(h, ln2w + l * 256, ln2b + l * 256,
                                             hnb);
    gemm_bf16<1><<<dim3(64, 16), 256, 0, stream>>>(
        hnb, wt + 1441792 + (size_t)l * 262144, b1 + l * 1024, midb, 4096,
        1024, 256);
    gemm_bf16<2><<<dim3(64, 4), 256, 0, stream>>>(
        midb, wt + 2490368 + (size_t)l * 262144, b2 + l * 256, h, 4096, 256,
        1024);
  }

  final_kernel<<<1, 64, 0, stream>>>(h, encw, encb, nw, nb, (float*)d_out);
}

// Round 4
// 726.980 us; speedup vs baseline: 5.2924x; 1.0001x over previous
//
#include <hip/hip_runtime.h>
#include <hip/hip_bf16.h>
#include <math.h>

// ---------------------------------------------------------------------------
// LongNetViT forward. L=4096 (cls+4095), D=256, H=8, HD=32, DEPTH=4.
// bf16 MFMA everywhere (fp32 accumulate, fp32 residual stream).
// Branches at L=4096: b0 r=1 m=1024 segs=4 | b1 r=2 m=2048 (split into two
// 1024-key halves -> slots 1,2) | b2 r=4 m=1024 | b3 r=8 m=512 | b4 r=16 m=256
// ---------------------------------------------------------------------------

typedef __attribute__((ext_vector_type(8))) short short8;
typedef __attribute__((ext_vector_type(4))) float f32x4;

__device__ __forceinline__ float wred_sum(float v) {
#pragma unroll
  for (int o = 32; o; o >>= 1) v += __shfl_xor(v, o);
  return v;
}

__device__ __forceinline__ unsigned short f2bf(float x) {
  unsigned u = __float_as_uint(x);
  u += 0x7FFF + ((u >> 16) & 1);
  return (unsigned short)(u >> 16);
}
__device__ __forceinline__ float bf2f(unsigned short s) {
  return __uint_as_float(((unsigned)s) << 16);
}

// ---------------------------------------------------------------------------
// bf16 MFMA GEMM, zero-LDS. C[M,N] = epi(A[M,K]bf16 @ Bt[N,K]bf16^T + bias).
// EPI: 0 = f32 out, 1 = GELU -> bf16 out, 2 = residual add into f32 C,
// 3 = bf16 out.
// ---------------------------------------------------------------------------
template <int EPI>
__global__ __launch_bounds__(256) void gemm_bf16(
    const unsigned short* __restrict__ A, const unsigned short* __restrict__ Bt,
    const float* __restrict__ bias, void* __restrict__ Cv, int M, int N,
    int K) {
  const int lane = threadIdx.x & 63, w = threadIdx.x >> 6;
  const int g = lane >> 4, q = lane & 15;
  const int bm = blockIdx.x * 64, bn = blockIdx.y * 64;

  int arow = bm + 16 * w + q;
  int ar = arow < M ? arow : M - 1;
  const unsigned short* ap = A + (size_t)ar * K + 8 * g;
  const unsigned short* bp = Bt + (size_t)(bn + q) * K + 8 * g;

  f32x4 acc[4];
#pragma unroll
  for (int i = 0; i < 4; i++) acc[i] = (f32x4){0.f, 0.f, 0.f, 0.f};

#pragma unroll 2
  for (int k0 = 0; k0 < K; k0 += 32) {
    short8 af = *(const short8*)(ap + k0);
#pragma unroll
    for (int cf = 0; cf < 4; cf++) {
      short8 bf = *(const short8*)(bp + (size_t)(16 * cf) * K + k0);
      acc[cf] = __builtin_amdgcn_mfma_f32_16x16x32_bf16(af, bf, acc[cf], 0, 0, 0);
    }
  }

  const int orow0 = bm + 16 * w + 4 * g;
#pragma unroll
  for (int cf = 0; cf < 4; cf++) {
    const int col = bn + 16 * cf + q;
    const float bs = bias[col];
#pragma unroll
    for (int rg = 0; rg < 4; rg++) {
      int orow = orow0 + rg;
      if (orow < M) {
        float c = acc[cf][rg] + bs;
        size_t idx = (size_t)orow * N + col;
        if (EPI == 1) {
          c = 0.5f * c * (1.f + erff(c * 0.70710678118654752f));
          ((unsigned short*)Cv)[idx] = f2bf(c);
        } else if (EPI == 3) {
          ((unsigned short*)Cv)[idx] = f2bf(c);
        } else if (EPI == 2) {
          float* p = (float*)Cv;
          p[idx] += c;
        } else {
          ((float*)Cv)[idx] = c;
        }
      }
    }
  }
}

// ---------------------------------------------------------------------------
// Fused prepass: bid < 3072 -> x f32->bf16; else weight transpose to
// Bt[N][K] bf16 (17 tensors, offsets hardcoded).
// ---------------------------------------------------------------------------
__global__ __launch_bounds__(256) void prep_kernel(
    const float* __restrict__ x, unsigned short* __restrict__ xb,
    const float* __restrict__ pw, const float* __restrict__ wqkv,
    const float* __restrict__ wo, const float* __restrict__ w1,
    const float* __restrict__ w2, unsigned short* __restrict__ wt) {
  __shared__ float T[32][33];
  if (blockIdx.x < 3072) {
    const int i = blockIdx.x * 256 + threadIdx.x;
    if (i >= 786240) return;  // 6289920 / 8
    const float4 a = *(const float4*)(x + (size_t)i * 8);
    const float4 b = *(const float4*)(x + (size_t)i * 8 + 4);
    unsigned u0 = (unsigned)f2bf(a.x) | ((unsigned)f2bf(a.y) << 16);
    unsigned u1 = (unsigned)f2bf(a.z) | ((unsigned)f2bf(a.w) << 16);
    unsigned u2 = (unsigned)f2bf(b.x) | ((unsigned)f2bf(b.y) << 16);
    unsigned u3 = (unsigned)f2bf(b.z) | ((unsigned)f2bf(b.w) << 16);
    *(uint4*)(xb + (size_t)i * 8) = make_uint4(u0, u1, u2, u3);
    return;
  }
  const int bid = blockIdx.x - 3072;
  const float* src;
  int Kd, Nd, lt;
  size_t doff;
  if (bid < 384) {
    src = pw; Kd = 1536; Nd = 256; doff = 0; lt = bid;
  } else if (bid < 1152) {
    int l = (bid - 384) / 192, r = (bid - 384) % 192;
    src = wqkv + (size_t)l * 196608; Kd = 256; Nd = 768;
    doff = 393216 + (size_t)l * 196608; lt = r;
  } else if (bid < 1408) {
    int l = (bid - 1152) / 64, r = (bid - 1152) % 64;
    src = wo + (size_t)l * 65536; Kd = 256; Nd = 256;
    doff = 1179648 + (size_t)l * 65536; lt = r;
  } else if (bid < 2432) {
    int l = (bid - 1408) / 256, r = (bid - 1408) % 256;
    src = w1 + (size_t)l * 262144; Kd = 256; Nd = 1024;
    doff = 1441792 + (size_t)l * 262144; lt = r;
  } else {
    int l = (bid - 2432) / 256, r = (bid - 2432) % 256;
    src = w2 + (size_t)l * 262144; Kd = 1024; Nd = 256;
    doff = 2490368 + (size_t)l * 262144; lt = r;
  }
  const int tilesK = Kd >> 5;
  const int tn = lt / tilesK, tk = lt % tilesK;
  const int k0 = tk * 32, n0 = tn * 32;
  const int t = threadIdx.x;
  const int rr = t >> 3, c4 = t & 7;
  float4 v = *(const float4*)(src + (size_t)(k0 + rr) * Nd + n0 + c4 * 4);
  T[rr][c4 * 4 + 0] = v.x;
  T[rr][c4 * 4 + 1] = v.y;
  T[rr][c4 * 4 + 2] = v.z;
  T[rr][c4 * 4 + 3] = v.w;
  __syncthreads();
  float o0 = T[c4 * 4 + 0][rr], o1 = T[c4 * 4 + 1][rr];
  float o2 = T[c4 * 4 + 2][rr], o3 = T[c4 * 4 + 3][rr];
  unsigned u0 = (unsigned)f2bf(o0) | ((unsigned)f2bf(o1) << 16);
  unsigned u1 = (unsigned)f2bf(o2) | ((unsigned)f2bf(o3) << 16);
  *(uint2*)(wt + doff + (size_t)(n0 + rr) * Kd + k0 + c4 * 4) =
      make_uint2(u0, u1);
}

// ---------------------------------------------------------------------------
// LayerNorm over D=256, bf16 out; one wave per row, 4 rows per block.
// ---------------------------------------------------------------------------
__global__ __launch_bounds__(256) void ln_bf16_kernel(
    const float* __restrict__ x, const float* __restrict__ w,
    const float* __restrict__ b, unsigned short* __restrict__ y) {
  const int row = blockIdx.x * 4 + (threadIdx.x >> 6);
  const int lane = threadIdx.x & 63;
  float4 v = *(const float4*)(x + (size_t)row * 256 + lane * 4);
  float s1 = wred_sum(v.x + v.y + v.z + v.w);
  float s2 = wred_sum(v.x * v.x + v.y * v.y + v.z * v.z + v.w * v.w);
  float mu = s1 * (1.f / 256.f);
  float inv = rsqrtf(s2 * (1.f / 256.f) - mu * mu + 1e-5f);
  float4 wv = *(const float4*)(w + lane * 4);
  float4 bv = *(const float4*)(b + lane * 4);
  float o0 = (v.x - mu) * inv * wv.x + bv.x;
  float o1 = (v.y - mu) * inv * wv.y + bv.y;
  float o2 = (v.z - mu) * inv * wv.z + bv.z;
  float o3 = (v.w - mu) * inv * wv.w + bv.w;
  unsigned u0 = (unsigned)f2bf(o0) | ((unsigned)f2bf(o1) << 16);
  unsigned u1 = (unsigned)f2bf(o2) | ((unsigned)f2bf(o3) << 16);
  *(uint2*)(y + (size_t)row * 256 + lane * 4) = make_uint2(u0, u1);
}

// ---------------------------------------------------------------------------
__global__ __launch_bounds__(64) void assemble_kernel(
    const float* __restrict__ coords, const float* __restrict__ cls,
    const float* __restrict__ pe, float* __restrict__ h) {
  const int i = blockIdx.x;
  const int lane = threadIdx.x;
  if (i == 0) {
    float4 c = *(const float4*)(cls + lane * 4);
    float4 p = *(const float4*)(pe + lane * 4);
    *(float4*)(h + lane * 4) =
        make_float4(c.x + p.x, c.y + p.y, c.z + p.z, c.w + p.w);
  } else {
    int g0 = (int)floorf(coords[(size_t)(i - 1) * 2 + 0] * (1.f / 256.f));
    int g1 = (int)floorf(coords[(size_t)(i - 1) * 2 + 1] * (1.f / 256.f));
    int pos = g0 * 512 + g1 + 1;
    float4 p = *(const float4*)(pe + (size_t)pos * 256 + lane * 4);
    float4 hv = *(const float4*)(h + (size_t)i * 256 + lane * 4);
    *(float4*)(h + (size_t)i * 256 + lane * 4) =
        make_float4(hv.x + p.x, hv.y + p.y, hv.z + p.z, hv.w + p.w);
  }
}

// ---------------------------------------------------------------------------
// Gather decode: 992 (unit, key-tile) blocks covering all panels.
// ub = elem offset of the unit's panel in kg ([m][32]) and vt ([32][m]).
// ---------------------------------------------------------------------------
__device__ __forceinline__ void decode_gather(int bid, int& r, int& m,
                                              int& off, int& base, int& h,
                                              int& kt, int& ub) {
  if (bid < 512) {
    r = 1; m = 1024; int u = bid >> 4; kt = bid & 15;
    base = (u >> 3) * 1024; h = u & 7; off = 0; ub = u * 32768;
  } else if (bid < 768) {
    r = 2; m = 2048; int loc = bid - 512; h = loc >> 5; kt = loc & 31;
    base = 0; off = h & 1; ub = 1048576 + h * 65536;
  } else if (bid < 896) {
    r = 4; m = 1024; int loc = bid - 768; h = loc >> 4; kt = loc & 15;
    base = 0; off = h & 3; ub = 1572864 + h * 32768;
  } else if (bid < 960) {
    r = 8; m = 512; int loc = bid - 896; h = loc >> 3; kt = loc & 7;
    base = 0; off = h & 7; ub = 1835008 + h * 16384;
  } else {
    r = 16; m = 256; int loc = bid - 960; h = loc >> 2; kt = loc & 3;
    base = 0; off = h; ub = 1966080 + h * 8192;
  }
}

__global__ __launch_bounds__(256) void gather_kernel(
    const unsigned short* __restrict__ qkvb, unsigned short* __restrict__ kg,
    unsigned short* __restrict__ vt) {
  __shared__ unsigned short T[32][64];
  int r, m, off, base, h, kt, ub;
  decode_gather(blockIdx.x, r, m, off, base, h, kt, ub);
  const int t = threadIdx.x;
  {
    int key = t >> 2, c = t & 3;
    size_t row = base + off + (size_t)r * (kt * 64 + key);
    const unsigned short* src = qkvb + row * 768 + h * 32 + 8 * c;
    short8 kk = *(const short8*)(src + 256);
    *(short8*)(kg + ub + (size_t)(kt * 64 + key) * 32 + 8 * c) = kk;
    short8 vv = *(const short8*)(src + 512);
#pragma unroll
    for (int i = 0; i < 8; i++) T[8 * c + i][key] = (unsigned short)vv[i];
  }
  __syncthreads();
  int dim = t >> 3, c8 = t & 7;
  *(short8*)(vt + ub + (size_t)dim * m + kt * 64 + 8 * c8) =
      *(const short8*)&T[dim][8 * c8];
}

// ---------------------------------------------------------------------------
// Attention block decode: 1248 blocks, 6 output slots, <=16 key-tiles each.
// [0,512)    b0  slot0  nt=16
// [512,1024) b1  slots 1/2 (key halves of 1024)  nt=16
// [1024,1152) b2 slot3 nt=16 | [1152,1216) b3 slot4 nt=8 | [1216,1248) b4 slot5 nt=4
// ---------------------------------------------------------------------------
__device__ __forceinline__ void decode_attn(int bid, int& slot, int& r, int& m,
                                            int& nt, int& koff, int& off,
                                            int& base, int& h, int& qt,
                                            int& ub) {
  if (bid < 512) {
    slot = 0; r = 1; m = 1024; nt = 16; koff = 0;
    int u = bid >> 4; qt = bid & 15;
    base = (u >> 3) * 1024; h = u & 7; off = 0; ub = u * 32768;
  } else if (bid < 1024) {
    int loc = bid - 512; int half = loc >> 8; int l2 = loc & 255;
    slot = 1 + half; r = 2; m = 2048; nt = 16; koff = half * 1024;
    h = l2 >> 5; qt = l2 & 31; base = 0; off = h & 1;
    ub = 1048576 + h * 65536;
  } else if (bid < 1152) {
    slot = 3; r = 4; m = 1024; nt = 16; koff = 0;
    int loc = bid - 1024; h = loc >> 4; qt = loc & 15;
    base = 0; off = h & 3; ub = 1572864 + h * 32768;
  } else if (bid < 1216) {
    slot = 4; r = 8; m = 512; nt = 8; koff = 0;
    int loc = bid - 1152; h = loc >> 3; qt = loc & 7;
    base = 0; off = h & 7; ub = 1835008 + h * 16384;
  } else {
    slot = 5; r = 16; m = 256; nt = 4; koff = 0;
    int loc = bid - 1216; h = loc >> 2; qt = loc & 3;
    base = 0; off = h; ub = 1966080 + h * 8192;
  }
}

// ---------------------------------------------------------------------------
// bf16 MFMA flash attention, LDS-free, pipelined (V + next-K loads issued
// before softmax). 1248 blocks, 4 waves, 16 q-rows/wave. Swapped QK^T -> S^T;
// online softmax in-register; P^T re-fragmented via cvt_pk_bf16 + shfl;
// PV: O^T = Vt . P^T. Outputs bf16 + f32 lse.
// ---------------------------------------------------------------------------
__global__ __launch_bounds__(256) void attn_mfma_kernel(
    const unsigned short* __restrict__ qkvb,
    const unsigned short* __restrict__ kg, const unsigned short* __restrict__ vt,
    unsigned short* __restrict__ oa, float* __restrict__ lse_all) {
  int slot, r, m, nt, koff, off, base, h, qt, ub;
  decode_attn(blockIdx.x, slot, r, m, nt, koff, off, base, h, qt, ub);

  const int lane = threadIdx.x & 63;
  const int wid = threadIdx.x >> 6;
  const int g = lane >> 4, q = lane & 15;
  const int q0 = qt * 64 + wid * 16;

  const size_t qrow = base + off + (size_t)r * (q0 + q);
  short8 qf = *(const short8*)(qkvb + qrow * 768 + h * 32 + 8 * g);

  const unsigned short* kp = kg + ub + (size_t)(koff + q) * 32 + 8 * g;
  const unsigned short* vp = vt + ub + (size_t)q * m + koff + 8 * g;

  f32x4 ot0 = {0.f, 0.f, 0.f, 0.f}, ot1 = {0.f, 0.f, 0.f, 0.f};
  float rm = -1e30f, rl = 0.f;
  const float scale = 0.17677669529663687f;  // 1/sqrt(32)

  short8 kf[4];
#pragma unroll
  for (int a = 0; a < 4; a++) kf[a] = *(const short8*)(kp + (size_t)(16 * a) * 32);

  for (int kt = 0; kt < nt; ++kt) {
    const int k0 = kt * 64;
    // V loads for this tile (independent of softmax -> issue early)
    short8 va0 = *(const short8*)(vp + k0);
    short8 va1 = *(const short8*)(vp + k0 + 32);
    short8 vb0 = *(const short8*)(vp + (size_t)16 * m + k0);
    short8 vb1 = *(const short8*)(vp + (size_t)16 * m + k0 + 32);

    f32x4 st[4];
#pragma unroll
    for (int a = 0; a < 4; a++) {
      f32x4 z = {0.f, 0.f, 0.f, 0.f};
      st[a] = __builtin_amdgcn_mfma_f32_16x16x32_bf16(kf[a], qf, z, 0, 0, 0);
    }
    // prefetch next tile's K fragments (hidden under softmax)
    if (kt + 1 < nt) {
#pragma unroll
      for (int a = 0; a < 4; a++)
        kf[a] = *(const short8*)(kp + (size_t)(k0 + 64 + 16 * a) * 32);
    }

    float p[4][4];
    float mx = -1e30f;
#pragma unroll
    for (int a = 0; a < 4; a++)
#pragma unroll
      for (int rr = 0; rr < 4; rr++) {
        p[a][rr] = st[a][rr] * scale;
        mx = fmaxf(mx, p[a][rr]);
      }
    mx = fmaxf(mx, __shfl_xor(mx, 16));
    mx = fmaxf(mx, __shfl_xor(mx, 32));
    float nm = fmaxf(rm, mx);
    float corr = __expf(rm - nm);
    float tl = 0.f;
#pragma unroll
    for (int a = 0; a < 4; a++)
#pragma unroll
      for (int rr = 0; rr < 4; rr++) {
        p[a][rr] = __expf(p[a][rr] - nm);
        tl += p[a][rr];
      }
    tl += __shfl_xor(tl, 16);
    tl += __shfl_xor(tl, 32);
    rl = rl * corr + tl;
    rm = nm;
    ot0 *= corr;
    ot1 *= corr;

    unsigned pk[4][2];
#pragma unroll
    for (int a = 0; a < 4; a++) {
      asm("v_cvt_pk_bf16_f32 %0, %1, %2"
          : "=v"(pk[a][0]) : "v"(p[a][0]), "v"(p[a][1]));
      asm("v_cvt_pk_bf16_f32 %0, %1, %2"
          : "=v"(pk[a][1]) : "v"(p[a][2]), "v"(p[a][3]));
    }

#pragma unroll
    for (int kk = 0; kk < 2; kk++) {
      union { unsigned w[4]; short8 v; } pb;
#pragma unroll
      for (int jj = 0; jj < 2; jj++) {
        int src = q + 16 * ((2 * g + jj) & 3);
#pragma unroll
        for (int d = 0; d < 2; d++) {
          unsigned lo = (unsigned)__shfl((int)pk[2 * kk + 0][d], src);
          unsigned hi = (unsigned)__shfl((int)pk[2 * kk + 1][d], src);
          pb.w[jj * 2 + d] = (g >> 1) ? hi : lo;
        }
      }
      if (kk == 0) {
        ot0 = __builtin_amdgcn_mfma_f32_16x16x32_bf16(va0, pb.v, ot0, 0, 0, 0);
        ot1 = __builtin_amdgcn_mfma_f32_16x16x32_bf16(vb0, pb.v, ot1, 0, 0, 0);
      } else {
        ot0 = __builtin_amdgcn_mfma_f32_16x16x32_bf16(va1, pb.v, ot0, 0, 0, 0);
        ot1 = __builtin_amdgcn_mfma_f32_16x16x32_bf16(vb1, pb.v, ot1, 0, 0, 0);
      }
    }
  }

  float inv = 1.f / rl;
  int pos = base + off + r * (q0 + q);
  size_t ob = (((size_t)slot * 4096 + pos) * 8 + h) * 32;
  unsigned w0 = (unsigned)f2bf(ot0[0] * inv) | ((unsigned)f2bf(ot0[1] * inv) << 16);
  unsigned w1 = (unsigned)f2bf(ot0[2] * inv) | ((unsigned)f2bf(ot0[3] * inv) << 16);
  unsigned w2 = (unsigned)f2bf(ot1[0] * inv) | ((unsigned)f2bf(ot1[1] * inv) << 16);
  unsigned w3 = (unsigned)f2bf(ot1[2] * inv) | ((unsigned)f2bf(ot1[3] * inv) << 16);
  *(uint2*)(oa + ob + 4 * g) = make_uint2(w0, w1);
  *(uint2*)(oa + ob + 16 + 4 * g) = make_uint2(w2, w3);
  if (g == 0)
    lse_all[((size_t)slot * 4096 + pos) * 8 + h] = rm + __logf(rl);
}

// ---------------------------------------------------------------------------
// Combine 6 slots per (pos, head) by LSE softmax; bf16 out.
// Slot coverage: 0 always; 1,2: (pos^h)&1==0; 3: &3; 4: &7; 5: &15.
// ---------------------------------------------------------------------------
__global__ __launch_bounds__(256) void combine_kernel(
    const unsigned short* __restrict__ oa, const float* __restrict__ lse_all,
    unsigned short* __restrict__ att) {
  const int tid = blockIdx.x * 256 + threadIdx.x;  // 524288 total
  const int pos = tid >> 7;
  const int ph = (tid >> 4) & 7;
  const int d0 = (tid & 15) * 2;

  const int msk[6] = {0, 1, 1, 3, 7, 15};
  float lse[6];
  bool cov[6];
#pragma unroll
  for (int s = 0; s < 6; s++) {
    cov[s] = ((pos ^ ph) & msk[s]) == 0;
    lse[s] = cov[s] ? lse_all[((size_t)s * 4096 + pos) * 8 + ph] : -3.0e38f;
  }
  float mx = lse[0];
#pragma unroll
  for (int s = 1; s < 6; s++) mx = fmaxf(mx, lse[s]);
  float wsum = 0.f, o0 = 0.f, o1 = 0.f;
#pragma unroll
  for (int s = 0; s < 6; s++) {
    if (cov[s]) {
      float w = __expf(lse[s] - mx);
      wsum += w;
      unsigned u = *(const unsigned*)(oa +
          (((size_t)s * 4096 + pos) * 8 + ph) * 32 + d0);
      o0 += w * bf2f((unsigned short)(u & 0xFFFF));
      o1 += w * bf2f((unsigned short)(u >> 16));
    }
  }
  float inv = 1.f / wsum;
  unsigned u = (unsigned)f2bf(o0 * inv) | ((unsigned)f2bf(o1 * inv) << 16);
  *(unsigned*)(att + (size_t)pos * 256 + ph * 32 + d0) = u;
}

// ---------------------------------------------------------------------------
__global__ __launch_bounds__(64) void final_kernel(
    const float* __restrict__ h, const float* __restrict__ ew,
    const float* __restrict__ eb, const float* __restrict__ nw,
    const float* __restrict__ nb, float* __restrict__ out) {
  const int lane = threadIdx.x;
  float4 v = *(const float4*)(h + lane * 4);
  float s1 = wred_sum(v.x + v.y + v.z + v.w);
  float s2 = wred_sum(v.x * v.x + v.y * v.y + v.z * v.z + v.w * v.w);
  float mu = s1 * (1.f / 256.f);
  float inv = rsqrtf(s2 * (1.f / 256.f) - mu * mu + 1e-5f);
  float4 wv = *(const float4*)(ew + lane * 4);
  float4 bv = *(const float4*)(eb + lane * 4);
  float4 tv;
  tv.x = (v.x - mu) * inv * wv.x + bv.x;
  tv.y = (v.y - mu) * inv * wv.y + bv.y;
  tv.z = (v.z - mu) * inv * wv.z + bv.z;
  tv.w = (v.w - mu) * inv * wv.w + bv.w;
  s1 = wred_sum(tv.x + tv.y + tv.z + tv.w);
  s2 = wred_sum(tv.x * tv.x + tv.y * tv.y + tv.z * tv.z + tv.w * tv.w);
  mu = s1 * (1.f / 256.f);
  inv = rsqrtf(s2 * (1.f / 256.f) - mu * mu + 1e-5f);
  float4 w2v = *(const float4*)(nw + lane * 4);
  float4 b2v = *(const float4*)(nb + lane * 4);
  float4 o;
  o.x = (tv.x - mu) * inv * w2v.x + b2v.x;
  o.y = (tv.y - mu) * inv * w2v.y + b2v.y;
  o.z = (tv.z - mu) * inv * w2v.z + b2v.z;
  o.w = (tv.w - mu) * inv * w2v.w + b2v.w;
  *(float4*)(out + lane * 4) = o;
}

// ---------------------------------------------------------------------------

extern "C" void kernel_launch(void* const* d_in, const int* in_sizes, int n_in,
                              void* d_out, int out_size, void* d_ws,
                              size_t ws_size, hipStream_t stream) {
  const float* x      = (const float*)d_in[0];
  const float* coords = (const float*)d_in[1];
  const float* pw     = (const float*)d_in[2];
  const float* pb     = (const float*)d_in[3];
  const float* cls    = (const float*)d_in[4];
  const float* pe     = (const float*)d_in[5];
  const float* ln1w   = (const float*)d_in[6];
  const float* ln1b   = (const float*)d_in[7];
  const float* wqkv   = (const float*)d_in[8];
  const float* bqkv   = (const float*)d_in[9];
  const float* wo     = (const float*)d_in[10];
  const float* bo     = (const float*)d_in[11];
  const float* ln2w   = (const float*)d_in[12];
  const float* ln2b   = (const float*)d_in[13];
  const float* w1     = (const float*)d_in[14];
  const float* b1     = (const float*)d_in[15];
  const float* w2     = (const float*)d_in[16];
  const float* b2     = (const float*)d_in[17];
  const float* encw   = (const float*)d_in[18];
  const float* encb   = (const float*)d_in[19];
  const float* nw     = (const float*)d_in[20];
  const float* nb     = (const float*)d_in[21];

  float* ws = (float*)d_ws;
  float* h              = ws;                                // 1,048,576 f32
  unsigned short* hnb   = (unsigned short*)(ws + 1048576);   // 1,048,576 us
  unsigned short* qkvb  = (unsigned short*)(ws + 1572864);   // 3,145,728 us
  unsigned short* kg    = (unsigned short*)(ws + 3145728);   // 2,031,616 us
  unsigned short* vt    = (unsigned short*)(ws + 4194304);   // 2,031,616 us
  unsigned short* oa    = (unsigned short*)(ws + 5242880);   // 6,291,456 us
  float* lse            = ws + 8388608;                      //   196,608 f32
  unsigned short* attb  = (unsigned short*)(ws + 8650752);   // 1,048,576 us
  unsigned short* midb  = (unsigned short*)(ws + 9175040);   // 4,194,304 us
  unsigned short* xb    = (unsigned short*)(ws + 11272192);  // 6,289,920 us
  unsigned short* wt    = (unsigned short*)(ws + 14417920);  // 3,538,944 us
  // total ~16.2M f32 slots ~= 65 MiB

  prep_kernel<<<6528, 256, 0, stream>>>(x, xb, pw, wqkv, wo, w1, w2, wt);

  gemm_bf16<0><<<dim3(64, 4), 256, 0, stream>>>(xb, wt, pb, h + 256, 4095, 256,
                                                1536);
  assemble_kernel<<<4096, 64, 0, stream>>>(coords, cls, pe, h);

  for (int l = 0; l < 4; l++) {
    ln_bf16_kernel<<<1024, 256, 0, stream>>>(h, ln1w + l * 256, ln1b + l * 256,
                                             hnb);
    gemm_bf16<3><<<dim3(64, 12), 256, 0, stream>>>(
        hnb, wt + 393216 + (size_t)l * 196608, bqkv + l * 768, qkvb, 4096, 768,
        256);
    gather_kernel<<<992, 256, 0, stream>>>(qkvb, kg, vt);
    attn_mfma_kernel<<<1248, 256, 0, stream>>>(qkvb, kg, vt, oa, lse);
    combine_kernel<<<2048, 256, 0, stream>>>(oa, lse, attb);
    gemm_bf16<2><<<dim3(64, 4), 256, 0, stream>>>(
        attb, wt + 1179648 + (size_t)l * 65536, bo + l * 256, h, 4096, 256,
        256);
    ln_bf16_kernel<<<1024, 256, 0, stream>>>(h, ln2w + l * 256, ln2b + l * 256,
                                             hnb);
    gemm_bf16<1><<<dim3(64, 16), 256, 0, stream>>>(
        hnb, wt + 1441792 + (size_t)l * 262144, b1 + l * 1024, midb, 4096,
        1024, 256);
    gemm_bf16<2><<<dim3(64, 4), 256, 0, stream>>>(
        midb, wt + 2490368 + (size_t)l * 262144, b2 + l * 256, h, 4096, 256,
        1024);
  }

  final_kernel<<<1, 64, 0, stream>>>(h, encw, encb, nw, nb, (float*)d_out);
}